// Round 11
// baseline (94.503 us; speedup 1.0000x reference)
//
#include <hip/hip_runtime.h>
#include <cstddef>

#define BN_EPS 1e-5f

__device__ __forceinline__ float sigmoidf_(float x) {
    return __builtin_amdgcn_rcpf(1.0f + __expf(-x));
}

// Division/exp-free sigmoid for x >= 0: clamped cubic, P(0)=0.5 exact,
// max err ~0.0075 on [0,5], <=0.0067 beyond (clamp).  Validated in R8.
__device__ __forceinline__ float sig_poly_(float x) {
    float t = fminf(x, 5.0f);
    return fmaf(t, fmaf(t, fmaf(t, 0.003997859f, -0.05783463f), 0.28788663f), 0.5f);
}

__device__ __forceinline__ float sgpr_(float x) {   // force block-uniform -> SGPR
    return __uint_as_float(__builtin_amdgcn_readfirstlane(__float_as_uint(x)));
}

// K1: pool (blocks 0..1023) + lin partials (blocks 1024..1167).
// lin: thread -> (k, ch, bc); 50 fully-unrolled independent loads (all in
// flight) instead of 100 unroll-4 -> kills the 9us latency tail.
__global__ __launch_bounds__(256) void pool_lin_kernel(
    const float* __restrict__ value, const float* __restrict__ query,
    const float* __restrict__ Wl,
    float* __restrict__ pooled, float* __restrict__ linpart) {
    int t = threadIdx.x;
    if (blockIdx.x >= 1024) {
        int g  = (blockIdx.x - 1024) * 256 + t;   // 0..36863
        int bc = g & 1023;
        int rest = g >> 10;                       // 0..35
        int k = rest >> 1, ch = rest & 1;
        const float* qp = query + (size_t)(50 * ch) * 1024 + bc;
        const float* wp = Wl + k * 100 + 50 * ch;
        float s = 0.f;
        #pragma unroll
        for (int i = 0; i < 50; ++i) s = fmaf(qp[(size_t)i * 1024], wp[i], s);
        linpart[(bc * 18 + k) * 2 + ch] = s;
        return;
    }
    int bc = blockIdx.x;
    const float4* vp = (const float4*)(value + (size_t)bc * 4096);
    float s = 0.f;
    #pragma unroll
    for (int i = 0; i < 4; ++i) {
        float4 v = vp[t + 256 * i];
        s += v.x + v.y + v.z + v.w;
    }
    #pragma unroll
    for (int off = 32; off > 0; off >>= 1) s += __shfl_down(s, off);
    __shared__ float ws4[4];
    if ((t & 63) == 0) ws4[t >> 6] = s;
    __syncthreads();
    if (t == 0) pooled[bc] = (ws4[0] + ws4[1] + ws4[2] + ws4[3]) * (1.0f / 4096.0f);
}

// K2: dp = relu(BN(pooled @ W1^T + b1)) -> (4,1024).  One wave per output.
__global__ __launch_bounds__(256) void fc1_kernel(
    const float* __restrict__ pooled, const float* __restrict__ W1,
    const float* __restrict__ b1, const float* __restrict__ gamma,
    const float* __restrict__ beta, const float* __restrict__ mean,
    const float* __restrict__ var, float* __restrict__ dp) {
    int wid  = blockIdx.x * 4 + (threadIdx.x >> 6);   // 0..4095
    int lane = threadIdx.x & 63;
    int b = wid >> 10, j = wid & 1023;
    const float4* pr = (const float4*)(pooled + b * 256);
    const float4* wr = (const float4*)(W1 + (size_t)j * 256);
    float4 p = pr[lane], w = wr[lane];
    float s = p.x * w.x + p.y * w.y + p.z * w.z + p.w * w.w;
    #pragma unroll
    for (int off = 32; off > 0; off >>= 1) s += __shfl_down(s, off);
    if (lane == 0) {
        s += b1[j];
        s = (s - mean[j]) * rsqrtf(var[j] + BN_EPS) * gamma[j] + beta[j];
        dp[wid] = fmaxf(s, 0.f);
    }
}

// K3: fused fc2-gates + register-streaming two-stage 3x3 stencil + q proj.
// TWO blocks per (b,c) plane (grid 2048), wave handles 8 rows (R10 structure).
// NOTE: launched 6x this round to measure its true duration (idempotent).
__global__ __launch_bounds__(256, 6) void stencil_kernel(
    const float* __restrict__ value, const float* __restrict__ dp,
    const float* __restrict__ W2, const float* __restrict__ b2,
    const float* __restrict__ linpart, const float* __restrict__ bl,
    const float* __restrict__ Wd, const float* __restrict__ bd,
    float* __restrict__ q_out, float* __restrict__ y_out) {

    __shared__ float scat[18];
    __shared__ float gAB[2];

    const int t    = threadIdx.x;
    const int blk  = blockIdx.x;          // 0..2047
    const int bc   = blk >> 1;            // plane
    const int half = blk & 1;             // 0: rows 0..31, 1: rows 32..63
    const int b    = bc >> 8, c = bc & 255;
    const int w    = t >> 6, lane = t & 63;

    // fc2 gate dots (waves 0,1) -- redundantly per half-block
    if (w < 2) {
        const float4* dpr  = (const float4*)(dp + b * 1024);
        const float4* wrow = (const float4*)(W2 + (size_t)(c + w * 256) * 1024);
        float sg = 0.f;
        #pragma unroll
        for (int j = 0; j < 4; ++j) {
            float4 d = dpr[lane + 64 * j], ww = wrow[lane + 64 * j];
            sg += d.x * ww.x + d.y * ww.y + d.z * ww.z + d.w * ww.w;
        }
        #pragma unroll
        for (int off = 32; off > 0; off >>= 1) sg += __shfl_xor(sg, off);
        if (lane == 0) gAB[w] = sigmoidf_(sg + b2[c + w * 256]);
    }
    // lin = sum of 2 partials + bias
    float lv = 0.f;
    if (t < 18) {
        const float2 lp = ((const float2*)linpart)[bc * 18 + t];
        lv = lp.x + lp.y + bl[t];
    }
    __syncthreads();
    if (t < 18) scat[t] = lv * (t < 9 ? gAB[0] : gAB[1]);
    __syncthreads();

    float f[9], wk[9];                    // block-uniform -> SGPRs
    #pragma unroll
    for (int k = 0; k < 9; ++k) { f[k] = sgpr_(scat[k]); wk[k] = sgpr_(scat[9 + k]); }

    const int y0 = half * 32 + (w << 3);  // wave's 8-row band start
    const float* vp = value + (size_t)bc * 4096 + lane;
    float*       yp = y_out + (size_t)bc * 4096 + lane;

    // rolling window: rows A=y-2, B=y-1, C=y, D=y+1 (L,C,R each)
    float vA_l = 0.f, vA_c = 0.f, vA_r = 0.f;
    float vB_c = ((unsigned)(y0 - 2) < 64u) ? vp[(y0 - 2) * 64] : 0.f;
    float vC_c = ((unsigned)(y0 - 1) < 64u) ? vp[(y0 - 1) * 64] : 0.f;
    float vB_l = __shfl_up(vB_c, 1);   if (lane == 0)  vB_l = 0.f;
    float vB_r = __shfl_down(vB_c, 1); if (lane == 63) vB_r = 0.f;
    float vC_l = __shfl_up(vC_c, 1);   if (lane == 0)  vC_l = 0.f;
    float vC_r = __shfl_down(vC_c, 1); if (lane == 63) vC_r = 0.f;
    float p2_l = 0.f, p2_c = 0.f, p2_r = 0.f;
    float p1_l = 0.f, p1_c = 0.f, p1_r = 0.f;
    float ytP  = 0.f;

    #pragma unroll
    for (int k = 0; k < 10; ++k) {
        const int y = y0 - 1 + k;         // conv row this iteration
        float vD_c = ((unsigned)(y + 1) < 64u) ? vp[(y + 1) * 64] : 0.f;
        float vD_l = __shfl_up(vD_c, 1);   if (lane == 0)  vD_l = 0.f;
        float vD_r = __shfl_down(vD_c, 1); if (lane == 63) vD_r = 0.f;

        float ytN;
        ytN = f[0] * vB_l;
        ytN = fmaf(f[1], vB_c, ytN);
        ytN = fmaf(f[2], vB_r, ytN);
        ytN = fmaf(f[3], vC_l, ytN);
        ytN = fmaf(f[4], vC_c, ytN);
        ytN = fmaf(f[5], vC_r, ytN);
        ytN = fmaf(f[6], vD_l, ytN);
        ytN = fmaf(f[7], vD_c, ytN);
        ytN = fmaf(f[8], vD_r, ytN);
        float d    = vC_c - ytN;
        float p0_c = __expf(-d * d) * vC_c;          // prod at row y
        float p0_l = __shfl_up(p0_c, 1);   if (lane == 0)  p0_l = 0.f;
        float p0_r = __shfl_down(p0_c, 1); if (lane == 63) p0_r = 0.f;

        if (k >= 2) {                     // output row z = y-1
            const float pcc = p1_c;
            float acc = ytP;
            acc = fmaf(-sig_poly_(fabsf(p2_l - pcc)) * vA_l, wk[0], acc);
            acc = fmaf(-sig_poly_(fabsf(p2_c - pcc)) * vA_c, wk[1], acc);
            acc = fmaf(-sig_poly_(fabsf(p2_r - pcc)) * vA_r, wk[2], acc);
            acc = fmaf(-sig_poly_(fabsf(p1_l - pcc)) * vB_l, wk[3], acc);
            acc = fmaf(-sig_poly_(fabsf(p1_c - pcc)) * vB_c, wk[4], acc);
            acc = fmaf(-sig_poly_(fabsf(p1_r - pcc)) * vB_r, wk[5], acc);
            acc = fmaf(-sig_poly_(fabsf(p0_l - pcc)) * vC_l, wk[6], acc);
            acc = fmaf(-sig_poly_(fabsf(p0_c - pcc)) * vC_c, wk[7], acc);
            acc = fmaf(-sig_poly_(fabsf(p0_r - pcc)) * vC_r, wk[8], acc);
            yp[(y - 1) * 64] = acc;
        }
        vA_l = vB_l; vA_c = vB_c; vA_r = vB_r;
        vB_l = vC_l; vB_c = vC_c; vB_r = vC_r;
        vC_l = vD_l; vC_c = vD_c; vC_r = vD_r;
        p2_l = p1_l; p2_c = p1_c; p2_r = p1_r;
        p1_l = p0_l; p1_c = p0_c; p1_r = p0_r;
        ytP  = ytN;
    }

    // q projection: once per plane (half==0 block, threads 0..99)
    if (half == 0 && t < 100) {
        float s = bd[t];
        const float* wr = Wd + t * 18;
        #pragma unroll
        for (int k = 0; k < 18; ++k) s = fmaf(scat[k], wr[k], s);
        q_out[(size_t)t * 1024 + bc] = s;
    }
}

extern "C" void kernel_launch(void* const* d_in, const int* in_sizes, int n_in,
                              void* d_out, int out_size, void* d_ws, size_t ws_size,
                              hipStream_t stream) {
    const float* query = (const float*)d_in[0];
    const float* value = (const float*)d_in[1];
    // d_in[2] hard_sigmoid_masks: unused by the reference
    const float* W1    = (const float*)d_in[3];
    const float* b1    = (const float*)d_in[4];
    const float* gamma = (const float*)d_in[5];
    const float* beta  = (const float*)d_in[6];
    const float* mean  = (const float*)d_in[7];
    const float* var   = (const float*)d_in[8];
    const float* W2    = (const float*)d_in[9];
    const float* b2    = (const float*)d_in[10];
    const float* Wl    = (const float*)d_in[11];
    const float* bl    = (const float*)d_in[12];
    const float* Wd    = (const float*)d_in[13];
    const float* bd    = (const float*)d_in[14];

    float* ws = (float*)d_ws;
    float* pooled  = ws;            // 1024
    float* dp      = ws + 1024;     // 4096
    float* linpart = ws + 5120;     // 36864 (18432 x 2 chunks)

    float* q_out = (float*)d_out;            // 102400 floats
    float* y_out = (float*)d_out + 102400;   // 4194304 floats

    hipLaunchKernelGGL(pool_lin_kernel, dim3(1168), dim3(256), 0, stream,
                       value, query, Wl, pooled, linpart);
    hipLaunchKernelGGL(fc1_kernel,      dim3(1024), dim3(256), 0, stream,
                       pooled, W1, b1, gamma, beta, mean, var, dp);
    // 6 identical launches: marginal cost of the extra 5 measures the
    // stencil's true duration (kernel is idempotent).
    for (int rep = 0; rep < 6; ++rep) {
        hipLaunchKernelGGL(stencil_kernel, dim3(2048), dim3(256), 0, stream,
                           value, dp, W2, b2, linpart, bl, Wd, bd, q_out, y_out);
    }
}

// Round 12
// 26.559 us; speedup vs baseline: 3.5583x; 3.5583x over previous
//
#include <hip/hip_runtime.h>
#include <cstddef>

#define BN_EPS 1e-5f

__device__ __forceinline__ float sigmoidf_(float x) {
    return __builtin_amdgcn_rcpf(1.0f + __expf(-x));
}

// Division/exp-free sigmoid for x >= 0: clamped cubic, P(0)=0.5 exact,
// max err ~0.0075 on [0,5], <=0.0067 beyond (clamp).  Validated in R8.
__device__ __forceinline__ float sig_poly_(float x) {
    float t = fminf(x, 5.0f);
    return fmaf(t, fmaf(t, fmaf(t, 0.003997859f, -0.05783463f), 0.28788663f), 0.5f);
}

__device__ __forceinline__ float sgpr_(float x) {   // force block-uniform -> SGPR
    return __uint_as_float(__builtin_amdgcn_readfirstlane(__float_as_uint(x)));
}

// K1: pool (blocks 0..1023) + lin partials (blocks 1024..1167).
__global__ __launch_bounds__(256) void pool_lin_kernel(
    const float* __restrict__ value, const float* __restrict__ query,
    const float* __restrict__ Wl,
    float* __restrict__ pooled, float* __restrict__ linpart) {
    int t = threadIdx.x;
    if (blockIdx.x >= 1024) {
        int g  = (blockIdx.x - 1024) * 256 + t;   // 0..36863
        int bc = g & 1023;
        int rest = g >> 10;                       // 0..35
        int k = rest >> 1, ch = rest & 1;
        const float* qp = query + (size_t)(50 * ch) * 1024 + bc;
        const float* wp = Wl + k * 100 + 50 * ch;
        float s = 0.f;
        #pragma unroll
        for (int i = 0; i < 50; ++i) s = fmaf(qp[(size_t)i * 1024], wp[i], s);
        linpart[(bc * 18 + k) * 2 + ch] = s;
        return;
    }
    int bc = blockIdx.x;
    const float4* vp = (const float4*)(value + (size_t)bc * 4096);
    float s = 0.f;
    #pragma unroll
    for (int i = 0; i < 4; ++i) {
        float4 v = vp[t + 256 * i];
        s += v.x + v.y + v.z + v.w;
    }
    #pragma unroll
    for (int off = 32; off > 0; off >>= 1) s += __shfl_down(s, off);
    __shared__ float ws4[4];
    if ((t & 63) == 0) ws4[t >> 6] = s;
    __syncthreads();
    if (t == 0) pooled[bc] = (ws4[0] + ws4[1] + ws4[2] + ws4[3]) * (1.0f / 4096.0f);
}

// K2: dp = relu(BN(pooled @ W1^T + b1)) -> (4,1024).  One wave per output.
__global__ __launch_bounds__(256) void fc1_kernel(
    const float* __restrict__ pooled, const float* __restrict__ W1,
    const float* __restrict__ b1, const float* __restrict__ gamma,
    const float* __restrict__ beta, const float* __restrict__ mean,
    const float* __restrict__ var, float* __restrict__ dp) {
    int wid  = blockIdx.x * 4 + (threadIdx.x >> 6);   // 0..4095
    int lane = threadIdx.x & 63;
    int b = wid >> 10, j = wid & 1023;
    const float4* pr = (const float4*)(pooled + b * 256);
    const float4* wr = (const float4*)(W1 + (size_t)j * 256);
    float4 p = pr[lane], w = wr[lane];
    float s = p.x * w.x + p.y * w.y + p.z * w.z + p.w * w.w;
    #pragma unroll
    for (int off = 32; off > 0; off >>= 1) s += __shfl_down(s, off);
    if (lane == 0) {
        s += b1[j];
        s = (s - mean[j]) * rsqrtf(var[j] + BN_EPS) * gamma[j] + beta[j];
        dp[wid] = fmaxf(s, 0.f);
    }
}

// K3: fused fc2-gates + register-streaming two-stage 3x3 stencil + q proj.
// TWO blocks per (b,c) plane (grid 2048), wave handles 8 rows.
// __launch_bounds__(256, 8): cap 64 VGPR -> 8 waves/SIMD (R7's fused kernel
// used 52 VGPRs for a superset of this body, so 64 fits without spills).
__global__ __launch_bounds__(256, 8) void stencil_kernel(
    const float* __restrict__ value, const float* __restrict__ dp,
    const float* __restrict__ W2, const float* __restrict__ b2,
    const float* __restrict__ linpart, const float* __restrict__ bl,
    const float* __restrict__ Wd, const float* __restrict__ bd,
    float* __restrict__ q_out, float* __restrict__ y_out) {

    __shared__ float scat[18];
    __shared__ float gAB[2];

    const int t    = threadIdx.x;
    const int blk  = blockIdx.x;          // 0..2047
    const int bc   = blk >> 1;            // plane
    const int half = blk & 1;             // 0: rows 0..31, 1: rows 32..63
    const int b    = bc >> 8, c = bc & 255;
    const int w    = t >> 6, lane = t & 63;

    // fc2 gate dots (waves 0,1) -- redundantly per half-block
    if (w < 2) {
        const float4* dpr  = (const float4*)(dp + b * 1024);
        const float4* wrow = (const float4*)(W2 + (size_t)(c + w * 256) * 1024);
        float sg = 0.f;
        #pragma unroll
        for (int j = 0; j < 4; ++j) {
            float4 d = dpr[lane + 64 * j], ww = wrow[lane + 64 * j];
            sg += d.x * ww.x + d.y * ww.y + d.z * ww.z + d.w * ww.w;
        }
        #pragma unroll
        for (int off = 32; off > 0; off >>= 1) sg += __shfl_xor(sg, off);
        if (lane == 0) gAB[w] = sigmoidf_(sg + b2[c + w * 256]);
    }
    // lin = sum of 2 partials + bias
    float lv = 0.f;
    if (t < 18) {
        const float2 lp = ((const float2*)linpart)[bc * 18 + t];
        lv = lp.x + lp.y + bl[t];
    }
    __syncthreads();
    if (t < 18) scat[t] = lv * (t < 9 ? gAB[0] : gAB[1]);
    __syncthreads();

    float f[9], wk[9];                    // block-uniform -> SGPRs
    #pragma unroll
    for (int k = 0; k < 9; ++k) { f[k] = sgpr_(scat[k]); wk[k] = sgpr_(scat[9 + k]); }

    const int y0 = half * 32 + (w << 3);  // wave's 8-row band start
    const float* vp = value + (size_t)bc * 4096 + lane;
    float*       yp = y_out + (size_t)bc * 4096 + lane;

    // rolling window: rows A=y-2, B=y-1, C=y, D=y+1 (L,C,R each)
    float vA_l = 0.f, vA_c = 0.f, vA_r = 0.f;
    float vB_c = ((unsigned)(y0 - 2) < 64u) ? vp[(y0 - 2) * 64] : 0.f;
    float vC_c = ((unsigned)(y0 - 1) < 64u) ? vp[(y0 - 1) * 64] : 0.f;
    float vB_l = __shfl_up(vB_c, 1);   if (lane == 0)  vB_l = 0.f;
    float vB_r = __shfl_down(vB_c, 1); if (lane == 63) vB_r = 0.f;
    float vC_l = __shfl_up(vC_c, 1);   if (lane == 0)  vC_l = 0.f;
    float vC_r = __shfl_down(vC_c, 1); if (lane == 63) vC_r = 0.f;
    float p2_l = 0.f, p2_c = 0.f, p2_r = 0.f;
    float p1_l = 0.f, p1_c = 0.f, p1_r = 0.f;
    float ytP  = 0.f;

    #pragma unroll
    for (int k = 0; k < 10; ++k) {
        const int y = y0 - 1 + k;         // conv row this iteration
        float vD_c = ((unsigned)(y + 1) < 64u) ? vp[(y + 1) * 64] : 0.f;
        float vD_l = __shfl_up(vD_c, 1);   if (lane == 0)  vD_l = 0.f;
        float vD_r = __shfl_down(vD_c, 1); if (lane == 63) vD_r = 0.f;

        float ytN;
        ytN = f[0] * vB_l;
        ytN = fmaf(f[1], vB_c, ytN);
        ytN = fmaf(f[2], vB_r, ytN);
        ytN = fmaf(f[3], vC_l, ytN);
        ytN = fmaf(f[4], vC_c, ytN);
        ytN = fmaf(f[5], vC_r, ytN);
        ytN = fmaf(f[6], vD_l, ytN);
        ytN = fmaf(f[7], vD_c, ytN);
        ytN = fmaf(f[8], vD_r, ytN);
        float d    = vC_c - ytN;
        float p0_c = __expf(-d * d) * vC_c;          // prod at row y
        float p0_l = __shfl_up(p0_c, 1);   if (lane == 0)  p0_l = 0.f;
        float p0_r = __shfl_down(p0_c, 1); if (lane == 63) p0_r = 0.f;

        if (k >= 2) {                     // output row z = y-1
            const float pcc = p1_c;
            float acc = ytP;
            acc = fmaf(-sig_poly_(fabsf(p2_l - pcc)) * vA_l, wk[0], acc);
            acc = fmaf(-sig_poly_(fabsf(p2_c - pcc)) * vA_c, wk[1], acc);
            acc = fmaf(-sig_poly_(fabsf(p2_r - pcc)) * vA_r, wk[2], acc);
            acc = fmaf(-sig_poly_(fabsf(p1_l - pcc)) * vB_l, wk[3], acc);
            acc = fmaf(-sig_poly_(fabsf(p1_c - pcc)) * vB_c, wk[4], acc);
            acc = fmaf(-sig_poly_(fabsf(p1_r - pcc)) * vB_r, wk[5], acc);
            acc = fmaf(-sig_poly_(fabsf(p0_l - pcc)) * vC_l, wk[6], acc);
            acc = fmaf(-sig_poly_(fabsf(p0_c - pcc)) * vC_c, wk[7], acc);
            acc = fmaf(-sig_poly_(fabsf(p0_r - pcc)) * vC_r, wk[8], acc);
            yp[(y - 1) * 64] = acc;
        }
        vA_l = vB_l; vA_c = vB_c; vA_r = vB_r;
        vB_l = vC_l; vB_c = vC_c; vB_r = vC_r;
        vC_l = vD_l; vC_c = vD_c; vC_r = vD_r;
        p2_l = p1_l; p2_c = p1_c; p2_r = p1_r;
        p1_l = p0_l; p1_c = p0_c; p1_r = p0_r;
        ytP  = ytN;
    }

    // q projection: once per plane (half==0 block, threads 0..99)
    if (half == 0 && t < 100) {
        float s = bd[t];
        const float* wr = Wd + t * 18;
        #pragma unroll
        for (int k = 0; k < 18; ++k) s = fmaf(scat[k], wr[k], s);
        q_out[(size_t)t * 1024 + bc] = s;
    }
}

extern "C" void kernel_launch(void* const* d_in, const int* in_sizes, int n_in,
                              void* d_out, int out_size, void* d_ws, size_t ws_size,
                              hipStream_t stream) {
    const float* query = (const float*)d_in[0];
    const float* value = (const float*)d_in[1];
    // d_in[2] hard_sigmoid_masks: unused by the reference
    const float* W1    = (const float*)d_in[3];
    const float* b1    = (const float*)d_in[4];
    const float* gamma = (const float*)d_in[5];
    const float* beta  = (const float*)d_in[6];
    const float* mean  = (const float*)d_in[7];
    const float* var   = (const float*)d_in[8];
    const float* W2    = (const float*)d_in[9];
    const float* b2    = (const float*)d_in[10];
    const float* Wl    = (const float*)d_in[11];
    const float* bl    = (const float*)d_in[12];
    const float* Wd    = (const float*)d_in[13];
    const float* bd    = (const float*)d_in[14];

    float* ws = (float*)d_ws;
    float* pooled  = ws;            // 1024
    float* dp      = ws + 1024;     // 4096
    float* linpart = ws + 5120;     // 36864 (18432 x 2 chunks)

    float* q_out = (float*)d_out;            // 102400 floats
    float* y_out = (float*)d_out + 102400;   // 4194304 floats

    hipLaunchKernelGGL(pool_lin_kernel, dim3(1168), dim3(256), 0, stream,
                       value, query, Wl, pooled, linpart);
    hipLaunchKernelGGL(fc1_kernel,      dim3(1024), dim3(256), 0, stream,
                       pooled, W1, b1, gamma, beta, mean, var, dp);
    hipLaunchKernelGGL(stencil_kernel,  dim3(2048), dim3(256), 0, stream,
                       value, dp, W2, b2, linpart, bl, Wd, bd, q_out, y_out);
}